// Round 21
// baseline (82.418 us; speedup 1.0000x reference)
//
#include <hip/hip_runtime.h>
#include <hip/hip_bf16.h>

// Problem constants
#define BB 8
#define TT_ 4
#define TSEQ 1024
#define CEMB 512
#define NH 8
#define HD 64

typedef __attribute__((ext_vector_type(8))) short bf16x8;
typedef __attribute__((ext_vector_type(4))) float f32x4;
typedef __attribute__((ext_vector_type(16))) float f32x16;

#define AS1 __attribute__((address_space(1)))
#define AS3 __attribute__((address_space(3)))

__device__ __forceinline__ void gload_lds16(const void* g, void* l) {
  __builtin_amdgcn_global_load_lds((const AS1 unsigned int*)g, (AS3 unsigned int*)l, 16, 0, 0);
}

__device__ __forceinline__ short f2b(float f) {
  union { float f; unsigned u; } v; v.f = f;
  unsigned r = v.u + 0x7FFFu + ((v.u >> 16) & 1u);
  return (short)(r >> 16);
}

// T12: hardware packed f32->bf16 convert (no builtin on gfx950; inline asm)
__device__ __forceinline__ unsigned pack2(float a, float b) {
  unsigned r;
  asm("v_cvt_pk_bf16_f32 %0, %1, %2" : "=v"(r) : "v"(a), "v"(b));
  return r;
}

// ---------------------------------------------------------------------------
// Prep kernel: W transposes (0-255) + mask/perm (block 256).
// ---------------------------------------------------------------------------
__global__ __launch_bounds__(256) void k_prep(
    const float* __restrict__ w0, short* __restrict__ t0,
    const float* __restrict__ w1, short* __restrict__ t1,
    const void* __restrict__ pin, int* __restrict__ pme,
    int* __restrict__ perm, int* __restrict__ chunk_nkt)
{
  __shared__ float tsh[64][65];
  const int bid = blockIdx.x;

  if (bid < 256) {
    const int z = (bid >= 192);
    const int tile = z ? (bid - 192) : bid;
    const int ntx = z ? 8 : 24;
    const float* w = z ? w1 : w0;
    short* wt = z ? t1 : t0;
    const int N = z ? 512 : 1536, K = 512;
    const int tx = threadIdx.x & 15, ty = threadIdx.x >> 4;
    const int n0 = (tile % ntx) * 64, k0 = (tile / ntx) * 64;
#pragma unroll
    for (int i = 0; i < 4; ++i) {
      int kr = i * 16 + ty;
      float4 v = *(const float4*)&w[(size_t)(k0 + kr) * N + n0 + tx * 4];
      tsh[tx * 4 + 0][kr] = v.x; tsh[tx * 4 + 1][kr] = v.y;
      tsh[tx * 4 + 2][kr] = v.z; tsh[tx * 4 + 3][kr] = v.w;
    }
    __syncthreads();
#pragma unroll
    for (int i = 0; i < 4; ++i) {
      int nr = i * 16 + ty;
      short4 o;
      o.x = f2b(tsh[nr][tx * 4 + 0]); o.y = f2b(tsh[nr][tx * 4 + 1]);
      o.z = f2b(tsh[nr][tx * 4 + 2]); o.w = f2b(tsh[nr][tx * 4 + 3]);
      *(short4*)&wt[(size_t)(n0 + nr) * K + k0 + tx * 4] = o;
    }
    return;
  }

  // ---- mask detect + expand + permutation (single block) ----
  __shared__ int bad_f32, any_f32, bad_i32, any_i32, bad_u16, any_u16;
  if (threadIdx.x == 0) { bad_f32 = any_f32 = bad_i32 = any_i32 = bad_u16 = any_u16 = 0; }
  __syncthreads();
  const unsigned char* pb = (const unsigned char*)pin;
  const float* pf = (const float*)pin;
  const int* pi = (const int*)pin;
  const unsigned short* ph = (const unsigned short*)pin;
  for (int i = threadIdx.x; i < 1024; i += 256) {
    float fv = pf[i];
    if (fv != 0.0f && fv != 1.0f) bad_f32 = 1;
    if (fv == 1.0f) any_f32 = 1;
    int iv = pi[i];
    if (iv != 0 && iv != 1) bad_i32 = 1;
    if (iv == 1) any_i32 = 1;
  }
  for (int i = threadIdx.x; i < 2048; i += 256) {
    unsigned short hv = ph[i];
    if (hv != 0 && hv != 0x3F80u && hv != 0x3C00u) bad_u16 = 1;
    if (hv == 0x3F80u || hv == 0x3C00u) any_u16 = 1;
  }
  __syncthreads();
  int mode = 3;
  if (!bad_f32 && any_f32) mode = 0;
  else if (!bad_i32 && any_i32) mode = 1;
  else if (!bad_u16 && any_u16) mode = 2;
  for (int i = threadIdx.x; i < TT_ * TSEQ; i += 256) {
    int v;
    if (mode == 0)      v = (pf[i] != 0.0f);
    else if (mode == 1) v = (pi[i] != 0);
    else if (mode == 2) v = (ph[i] != 0);
    else                v = (pb[i] != 0);
    pme[i] = v;
  }
  __syncthreads();

  const int w = threadIdx.x >> 6, lane = threadIdx.x & 63;
  {
    const int* rowp = pme + w * 1024;
    unsigned long long bal[16];
    int npm = 0;
#pragma unroll
    for (int g = 0; g < 16; ++g) {
      bal[g] = __ballot(rowp[g * 64 + lane] != 0);
      npm += __popcll(bal[g]);
    }
    int off_non = 0, off_pm = 1024 - npm;
#pragma unroll
    for (int g = 0; g < 16; ++g) {
      unsigned long long m = bal[g];
      int below = __popcll(m & ((1ull << lane) - 1ull));
      int ispm = (int)((m >> lane) & 1ull);
      int pos = ispm ? (off_pm + below) : (off_non + lane - below);
      perm[w * 1024 + pos] = g * 64 + lane;
      int c = __popcll(m);
      off_pm += c; off_non += 64 - c;
    }
  }
  __syncthreads();
  {
    const int tt = w, c = (lane >> 3) & 7, seg = lane & 7;
    int mx = 0;
#pragma unroll
    for (int i = 0; i < 16; ++i) {
      int q = perm[tt * 1024 + c * 128 + seg * 16 + i];
      int need = pme[tt * 1024 + q] ? 16 : ((q >> 6) + 1);
      mx = mx > need ? mx : need;
    }
#pragma unroll
    for (int s = 1; s < 8; s <<= 1) {
      int o = __shfl_xor(mx, s, 64);
      mx = mx > o ? mx : o;
    }
    if (seg == 0) chunk_nkt[tt * 8 + c] = mx;
  }
}

// ---------------------------------------------------------------------------
// GEMM0 (QKV): 128x128 tile, 8 waves (wave tile 32x64), BK=32, DEPTH-3
// prefetch: A reg slots [3], A-LDS 3-buf, aload(k+3)/stageB(k+2)/awrite(k+1).
// Every HBM load now has TWO full iterations (~4000 cyc) in flight before
// its drain (R20 exposed ~500 cyc of the ~900-cyc x-stream latency per iter).
// Queue at top of iter k: [LA(k+1):2, SB(k):1, LA(k+2):2, SB(k+1):1]
//   -> vmcnt(3) steady; k=14 -> vmcnt(1); k=15 -> vmcnt(0).
// A direct from f32 x (reg-staged cvt_pk). Q pre-scaled by 0.125*log2(e).
// ---------------------------------------------------------------------------
__global__ __launch_bounds__(512) void k_gemm0(
    const float* __restrict__ X, const short* __restrict__ Bt,
    const float* __restrict__ bias,
    short* __restrict__ qb, short* __restrict__ kb, short* __restrict__ vtb)
{
  __shared__ short As[3][128 * 32];
  __shared__ short Bs[3][128 * 32];
  const int tid = threadIdx.x, lane = tid & 63, w = tid >> 6;   // w: 0..7
  const int wm = w >> 1, wn = w & 1;        // wave tile 32x64
  const int idp = (blockIdx.x & 7) * 96 + (blockIdx.x >> 3);
  const int n0 = (idp % 12) * 128, m0 = (idp / 12) * 128;
  f32x4 acc[2][4] = {};
  const char* Xbase = (const char*)X + (size_t)m0 * 2048;   // f32 row = 2048B
  const char* Bbase = (const char*)Bt + (size_t)n0 * 1024;
  const int arow = tid >> 2;                 // 0..127
  const int asub = (tid & 3);                // 32B f32 sub-chunk

  float4 ar[3][2];                           // A reg TRIPLE-buffer (static idx)

  auto aload = [&](int slot, int it) {       // 2x global_load_dwordx4 (vmcnt)
    const char* p = Xbase + (size_t)arow * 2048 + (size_t)it * 128 + asub * 32;
    ar[slot][0] = *(const float4*)p;
    ar[slot][1] = *(const float4*)(p + 16);
  };
  auto awrite = [&](int slot, int buf) {     // cvt + 1x ds_write_b128 (lgkm)
    union { unsigned u[4]; bf16x8 v; } o;
    float4 a = ar[slot][0], b2 = ar[slot][1];
    o.u[0] = pack2(a.x, a.y);  o.u[1] = pack2(a.z, a.w);
    o.u[2] = pack2(b2.x, b2.y); o.u[3] = pack2(b2.z, b2.w);
    *(bf16x8*)((char*)As[buf] + arow * 64 + asub * 16) = o.v;
  };
  auto stageB = [&](int buf, int it) {       // 1x gload_lds (vmcnt)
    gload_lds16(Bbase + (size_t)arow * 1024 + (size_t)it * 64 + asub * 16,
                (char*)Bs[buf] + w * 1024);
  };

  // prologue -> queue = [LA(1):2, SB(0):1, LA(2):2, SB(1):1]; As[0] written.
  aload(0, 0);                               // LA(0)
  aload(1, 1);                               // LA(1)
  asm volatile("s_waitcnt vmcnt(2)" ::: "memory");   // drain LA(0)
  awrite(0, 0);                              // W(0)
  stageB(0, 0);                              // SB(0)
  aload(2, 2);                               // LA(2)
  stageB(1, 1);                              // SB(1)

#pragma unroll
  for (int it = 0; it < 16; ++it) {
    // drain LA(it+1) (regs for W) + SB(it) (B for compute); deeper stays.
    if (it <= 13)      asm volatile("s_waitcnt vmcnt(3)" ::: "memory");
    else if (it == 14) asm volatile("s_waitcnt vmcnt(1)" ::: "memory");
    else               asm volatile("s_waitcnt vmcnt(0)" ::: "memory");
    if (it + 1 < 16) awrite((it + 1) % 3, (it + 1) % 3);
    if (it + 3 < 16) aload((it + 3) % 3, it + 3);   // (it+3)%3 == it%3
    asm volatile("s_waitcnt lgkmcnt(0)" ::: "memory");
    __builtin_amdgcn_s_barrier();
    if (it + 2 < 16) stageB((it + 2) % 3, it + 2);

    const short* Ab = As[it % 3];
    const short* Bb = Bs[it % 3];
    bf16x8 a[2], bfr[4];
#pragma unroll
    for (int mf = 0; mf < 2; ++mf)
      a[mf] = *(const bf16x8*)&Ab[(wm * 32 + mf * 16 + (lane & 15)) * 32 + (lane >> 4) * 8];
#pragma unroll
    for (int nf = 0; nf < 4; ++nf)
      bfr[nf] = *(const bf16x8*)&Bb[(wn * 64 + nf * 16 + (lane & 15)) * 32 + (lane >> 4) * 8];
#pragma unroll
    for (int mf = 0; mf < 2; ++mf)
#pragma unroll
      for (int nf = 0; nf < 4; ++nf)
        acc[mf][nf] = __builtin_amdgcn_mfma_f32_16x16x32_bf16(a[mf], bfr[nf], acc[mf][nf], 0, 0, 0);
  }

#pragma unroll
  for (int nf = 0; nf < 4; ++nf) {
    const int n_g = n0 + wn * 64 + nf * 16 + (lane & 15);
    const float bv = bias[n_g];
    const int which = n_g >> 9;
    const int c = n_g & 511;
    const int h = c >> 6, d = c & 63;
    const float qsc = (which == 0) ? 0.18033688011112043f : 1.0f;  // 0.125*log2(e)
#pragma unroll
    for (int mf = 0; mf < 2; ++mf) {
      const int mb = m0 + wm * 32 + mf * 16 + ((lane >> 4) << 2);
      const int b = mb >> 10, t0 = mb & 1023;
      const int b8h = b * NH + h;
      if (which == 2) {
        short4 pk;
        pk.x = f2b(acc[mf][nf][0] + bv);
        pk.y = f2b(acc[mf][nf][1] + bv);
        pk.z = f2b(acc[mf][nf][2] + bv);
        pk.w = f2b(acc[mf][nf][3] + bv);
        *(short4*)&vtb[((size_t)b8h * HD + d) * TSEQ + t0] = pk;
      } else {
        short* dst = (which == 0) ? qb : kb;
        size_t base = ((size_t)b8h * TSEQ + t0) * HD + d;
#pragma unroll
        for (int r = 0; r < 4; ++r)
          dst[base + (size_t)r * HD] = f2b((acc[mf][nf][r] + bv) * qsc);
      }
    }
  }
}

// ---------------------------------------------------------------------------
// GEMM1 (out-proj): R20-exact — 128x128 tile, 8 waves, 256 blocks, BK=32,
// 3-buf depth-2 counted vmcnt (A source yb is L2-warm; latency covered).
// ---------------------------------------------------------------------------
__global__ __launch_bounds__(512) void k_gemm1(
    const short* __restrict__ A, const short* __restrict__ Bt,
    const float* __restrict__ bias, float* __restrict__ fout)
{
  __shared__ short As[3][128 * 32];
  __shared__ short Bs[3][128 * 32];
  const int tid = threadIdx.x, lane = tid & 63, w = tid >> 6;
  const int wm = w >> 1, wn = w & 1;
  const int idp = (blockIdx.x & 7) * 32 + (blockIdx.x >> 3);
  const int n0 = (idp % 4) * 128, m0 = (idp / 4) * 128;
  f32x4 acc[2][4] = {};
  const char* Abase = (const char*)A + (size_t)m0 * 1024;
  const char* Bbase = (const char*)Bt + (size_t)n0 * 1024;
  const int arow = tid >> 2, asub = tid & 3;

  auto stage = [&](int buf, int it) {        // 2 loads/thread
    gload_lds16(Abase + (size_t)arow * 1024 + (size_t)it * 64 + asub * 16,
                (char*)As[buf] + w * 1024);
    gload_lds16(Bbase + (size_t)arow * 1024 + (size_t)it * 64 + asub * 16,
                (char*)Bs[buf] + w * 1024);
  };

  stage(0, 0);
  stage(1, 1);
#pragma unroll
  for (int it = 0; it < 16; ++it) {
    if (it < 15) asm volatile("s_waitcnt vmcnt(2)\n\ts_barrier" ::: "memory");
    else         asm volatile("s_waitcnt vmcnt(0)\n\ts_barrier" ::: "memory");
    if (it + 2 < 16) stage((it + 2) % 3, it + 2);
    const short* Ab = As[it % 3];
    const short* Bb = Bs[it % 3];
    bf16x8 a[2], bfr[4];
#pragma unroll
    for (int mf = 0; mf < 2; ++mf)
      a[mf] = *(const bf16x8*)&Ab[(wm * 32 + mf * 16 + (lane & 15)) * 32 + (lane >> 4) * 8];
#pragma unroll
    for (int nf = 0; nf < 4; ++nf)
      bfr[nf] = *(const bf16x8*)&Bb[(wn * 64 + nf * 16 + (lane & 15)) * 32 + (lane >> 4) * 8];
#pragma unroll
    for (int mf = 0; mf < 2; ++mf)
#pragma unroll
      for (int nf = 0; nf < 4; ++nf)
        acc[mf][nf] = __builtin_amdgcn_mfma_f32_16x16x32_bf16(a[mf], bfr[nf], acc[mf][nf], 0, 0, 0);
  }

#pragma unroll
  for (int nf = 0; nf < 4; ++nf) {
    const int n_g = n0 + wn * 64 + nf * 16 + (lane & 15);
    const float bv = bias[n_g];
#pragma unroll
    for (int mf = 0; mf < 2; ++mf) {
      const int mb = m0 + wm * 32 + mf * 16 + ((lane >> 4) << 2);
#pragma unroll
      for (int r = 0; r < 4; ++r)
        fout[(size_t)(mb + r) * 512 + n_g] = acc[mf][nf][r] + bv;
    }
  }
}

// ---------------------------------------------------------------------------
// Flash attention (R20-exact, unchanged).
// ---------------------------------------------------------------------------
__device__ __forceinline__ void pv_step(
    f32x16 p, int sub, int hi, int lq, const char* Vsb, f32x16& o0, f32x16& o1)
{
  unsigned P2[8];
#pragma unroll
  for (int i = 0; i < 8; ++i) P2[i] = pack2(p[2 * i], p[2 * i + 1]);
  unsigned e0 = __shfl_xor(hi ? P2[0] : P2[2], 32, 64);
  unsigned e1 = __shfl_xor(hi ? P2[1] : P2[3], 32, 64);
  unsigned e2 = __shfl_xor(hi ? P2[4] : P2[6], 32, 64);
  unsigned e3 = __shfl_xor(hi ? P2[5] : P2[7], 32, 64);
  union { unsigned u[4]; bf16x8 v; } f0, f1;
  f0.u[0] = hi ? e0 : P2[0]; f0.u[1] = hi ? e1 : P2[1];
  f0.u[2] = hi ? P2[2] : e0; f0.u[3] = hi ? P2[3] : e1;
  f1.u[0] = hi ? e2 : P2[4]; f1.u[1] = hi ? e3 : P2[5];
  f1.u[2] = hi ? P2[6] : e2; f1.u[3] = hi ? P2[7] : e3;
  __builtin_amdgcn_s_setprio(1);
#pragma unroll
  for (int dt = 0; dt < 2; ++dt) {
    int row = dt * 32 + lq;
    bf16x8 v0 = *(const bf16x8*)(Vsb + row * 128 + ((4 * sub + hi) ^ (row & 7)) * 16);
    bf16x8 v1 = *(const bf16x8*)(Vsb + row * 128 + ((4 * sub + 2 + hi) ^ (row & 7)) * 16);
    f32x16& o = dt ? o1 : o0;
    o = __builtin_amdgcn_mfma_f32_32x32x16_bf16(v0, f0.v, o, 0, 0, 0);
    o = __builtin_amdgcn_mfma_f32_32x32x16_bf16(v1, f1.v, o, 0, 0, 0);
  }
  __builtin_amdgcn_s_setprio(0);
}

__global__ __launch_bounds__(512) void k_attn(
    const short* __restrict__ qg, const short* __restrict__ kg,
    const short* __restrict__ vtg, const int* __restrict__ pme,
    const int* __restrict__ perm, const int* __restrict__ chunk_nkt,
    short* __restrict__ yb)
{
  __shared__ char smem[65536];
  const int tid = threadIdx.x, lane = tid & 63, w = tid >> 6;   // w: 0..7
  const int g = w >> 2;                         // KV-parity group
  const int hi = lane >> 5, lq = lane & 31;
  const int id = blockIdx.x;
  const int bh = id & 63, b = bh >> 3, h = bh & 7, tt = b & 3;
  const int chunk = 7 - (id >> 6);              // heavy chunks dispatched first
  const char* Qb = (const char*)(qg + (size_t)bh * TSEQ * HD);
  const char* Kb = (const char*)(kg + (size_t)bh * TSEQ * HD);
  const char* Vb = (const char*)(vtg + (size_t)bh * HD * TSEQ);

  const int stg_row = ((w & 3) << 3) + (lane >> 3);    // 0..31
  const int stg_cl = (lane & 7) ^ ((lane >> 3) & 7);   // pre-swizzled source chunk

  auto stage = [&](int buf, int kt) {                  // 4 loads/thread
#pragma unroll
    for (int is = 0; is < 2; ++is) {
      int row = is * 32 + stg_row;
      gload_lds16(Kb + (size_t)(kt * 64 + row) * 128 + stg_cl * 16,
                  smem + buf * 8192 + is * 4096 + (w & 3) * 1024);
      gload_lds16(Vb + (size_t)row * 2048 + kt * 128 + stg_cl * 16,
                  smem + 32768 + buf * 8192 + is * 4096 + (w & 3) * 1024);
    }
  };

  const int nkt = chunk_nkt[tt * 8 + chunk];
  const int q_g = perm[tt * 1024 + chunk * 128 + (w & 3) * 32 + lq];
  const int pmrow = pme[tt * TSEQ + q_g];

  if (g < nkt) stage(g * 2, g);   // prologue: A stages tile 0, B tile 1

  int wmq = q_g, wnq = q_g;
#pragma unroll
  for (int s = 1; s < 64; s <<= 1) {
    wmq = max(wmq, __shfl_xor(wmq, s, 64));
    wnq = min(wnq, __shfl_xor(wnq, s, 64));
  }
  const int whaspm = __any(pmrow != 0);

  bf16x8 qf[4];
#pragma unroll
  for (int dk = 0; dk < 4; ++dk)
    qf[dk] = *(const bf16x8*)(Qb + (size_t)q_g * 128 + dk * 32 + hi * 16);

  float mrun = -1e30f, lrun = 0.0f;
  f32x16 o0 = {}, o1 = {};

  const int niter = (nkt + 1) >> 1;
  for (int i = 0; i < niter; ++i) {
    asm volatile("s_waitcnt vmcnt(0)" ::: "memory");
    __builtin_amdgcn_s_barrier();
    const int kt = 2 * i + g;
    if (kt + 2 < nkt) stage(g * 2 + ((i + 1) & 1), kt + 2);

    const int kb_ = kt * 64;
    if (kt < nkt && (kb_ <= wmq || whaspm)) {
      const char* Ksb = smem + (g * 2 + (i & 1)) * 8192;
      const char* Vsb = smem + 32768 + (g * 2 + (i & 1)) * 8192;

      f32x16 s0 = {}, s1 = {};
      __builtin_amdgcn_s_setprio(1);
#pragma unroll
      for (int dk = 0; dk < 4; ++dk) {
        int row0 = lq, row1 = 32 + lq;
        bf16x8 kf0 = *(const bf16x8*)(Ksb + row0 * 128 + ((2 * dk + hi) ^ (row0 & 7)) * 16);
        bf16x8 kf1 = *(const bf16x8*)(Ksb + row1 * 128 + ((2 * dk + hi) ^ (row1 & 7)) * 16);
        s0 = __builtin_amdgcn_mfma_f32_32x32x16_bf16(kf0, qf[dk], s0, 0, 0, 0);
        s1 = __builtin_amdgcn_mfma_f32_32x32x16_bf16(kf1, qf[dk], s1, 0, 0, 0);
      }
      __builtin_amdgcn_s_setprio(0);

      if (kb_ + 63 <= wnq) {
        // fully attended
      } else if (kb_ > wmq) {
#pragma unroll
        for (int r = 0; r < 16; ++r) {
          s0[r] = pmrow ? s0[r] : -1e30f;
          s1[r] = pmrow ? s1[r] : -1e30f;
        }
      } else {
#pragma unroll
        for (int r = 0; r < 16; ++r) {
          int crow = (r & 3) + 8 * (r >> 2) + 4 * hi;
          s0[r] = ((kb_ + crow <= q_g) || pmrow) ? s0[r] : -1e30f;
          s1[r] = ((kb_ + 32 + crow <= q_g) || pmrow) ? s1[r] : -1e30f;
        }
      }

      float tm[16];
#pragma unroll
      for (int r = 0; r < 16; ++r) tm[r] = fmaxf(s0[r], s1[r]);
#pragma unroll
      for (int st = 8; st >= 1; st >>= 1)
#pragma unroll
        for (int r = 0; r < 8; ++r)
          if (r < st) tm[r] = fmaxf(tm[r], tm[r + st]);
      float mx = fmaxf(tm[0], __shfl_xor(tm[0], 32, 64));
      if (!__all(mx <= mrun + 8.0f)) {
        float nm = fmaxf(mrun, mx);
        float sc = __builtin_amdgcn_exp2f(mrun - nm);
        lrun *= sc;
#pragma unroll
        for (int r = 0; r < 16; ++r) { o0[r] *= sc; o1[r] *= sc; }
        mrun = nm;
      }
#pragma unroll
      for (int r = 0; r < 16; ++r) s0[r] = __builtin_amdgcn_exp2f(s0[r] - mrun);
#pragma unroll
      for (int r = 0; r < 16; ++r) s1[r] = __builtin_amdgcn_exp2f(s1[r] - mrun);
      float ts[16];
#pragma unroll
      for (int r = 0; r < 16; ++r) ts[r] = s0[r] + s1[r];
#pragma unroll
      for (int st = 8; st >= 1; st >>= 1)
#pragma unroll
        for (int r = 0; r < 8; ++r)
          if (r < st) ts[r] = ts[r] + ts[r + st];
      lrun += ts[0] + __shfl_xor(ts[0], 32, 64);

      pv_step(s0, 0, hi, lq, Vsb, o0, o1);
      pv_step(s1, 1, hi, lq, Vsb, o0, o1);
    }
  }

  // ---- merge groups A and B, stage y row-major in LDS, coalesced store ----
  __syncthreads();
  float* mg = (float*)smem;               // [256][34]: m, l, o[32]  (34816 B)
  short* ys = (short*)(smem + 36864);     // [128][72] bf16 rows     (18432 B)
  const int idx = (w & 3) * 64 + lane;
  if (g == 1) {
    mg[idx * 34 + 0] = mrun;
    mg[idx * 34 + 1] = lrun;
#pragma unroll
    for (int j = 0; j < 16; ++j) mg[idx * 34 + 2 + j] = o0[j];
#pragma unroll
    for (int j = 0; j < 16; ++j) mg[idx * 34 + 18 + j] = o1[j];
  }
  __syncthreads();
  if (g == 0) {
    const float mB = mg[idx * 34 + 0], lB = mg[idx * 34 + 1];
    const float m = fmaxf(mrun, mB);
    const float wa = __builtin_amdgcn_exp2f(mrun - m);
    const float wb = __builtin_amdgcn_exp2f(mB - m);
    const float linv = 1.0f / (lrun * wa + lB * wb);
    const float fa = wa * linv, fb = wb * linv;
    short* yl = ys + ((w & 3) * 32 + lq) * 72;
#pragma unroll
    for (int dt = 0; dt < 2; ++dt) {
      const f32x16& o = dt ? o1 : o0;
      const int ob = dt ? 18 : 2;
#pragma unroll
      for (int gg = 0; gg < 4; ++gg) {
        short4 pk;
        pk.x = f2b(o[4 * gg + 0] * fa + mg[idx * 34 + ob + 4 * gg + 0] * fb);
        pk.y = f2b(o[4 * gg + 1] * fa + mg[idx * 34 + ob + 4 * gg + 1] * fb);
        pk.z = f2b(o[4 * gg + 2] * fa + mg[idx * 34 + ob + 4 * gg + 2] * fb);
        pk.w = f2b(o[4 * gg + 3] * fa + mg[idx * 34 + ob + 4 * gg + 3] * fb);
        *(short4*)(yl + dt * 32 + 8 * gg + 4 * hi) = pk;
      }
    }
  }
  __syncthreads();
  {
    const int row = tid >> 2, seg = tid & 3;      // 4 threads/row x 32B
    const int q_row = perm[tt * 1024 + chunk * 128 + row];
    short* dst = yb + ((size_t)b * TSEQ + q_row) * CEMB + h * HD + seg * 16;
    *(bf16x8*)dst = *(const bf16x8*)&ys[row * 72 + seg * 16];
    *(bf16x8*)(dst + 8) = *(const bf16x8*)&ys[row * 72 + seg * 16 + 8];
  }
}

// ---------------------------------------------------------------------------
extern "C" void kernel_launch(void* const* d_in, const int* in_sizes, int n_in,
                              void* d_out, int out_size, void* d_ws, size_t ws_size,
                              hipStream_t stream) {
  const float* x     = (const float*)d_in[0];
  const void*  pmask = d_in[1];
  const float* Wqkv  = (const float*)d_in[2];
  const float* bqkv  = (const float*)d_in[3];
  const float* Wproj = (const float*)d_in[4];
  const float* bproj = (const float*)d_in[5];
  float* out = (float*)d_out;
  char* ws = (char*)d_ws;

  const size_t OFF_WQT  = 8388608;    // 1.5 MiB
  const size_t OFF_WPT  = 9961472;    // 0.5 MiB
  const size_t OFF_Q    = 10485760;   // 8 MiB
  const size_t OFF_K    = 18874368;   // 8 MiB
  const size_t OFF_VT   = 27262976;   // 8 MiB
  const size_t OFF_Y    = 35651584;   // 8 MiB
  const size_t OFF_PM   = 44040192;   // 16 KiB
  const size_t OFF_PERM = 44056576;   // 16 KiB
  const size_t OFF_CNKT = 44072960;   // 128 B
  const size_t NEED     = 44073984;
  if (ws_size < NEED) return;

  short* wqT = (short*)(ws + OFF_WQT);
  short* wpT = (short*)(ws + OFF_WPT);
  short* qb  = (short*)(ws + OFF_Q);
  short* kb  = (short*)(ws + OFF_K);
  short* vtb = (short*)(ws + OFF_VT);
  short* yb  = (short*)(ws + OFF_Y);
  int*   pme = (int*)(ws + OFF_PM);
  int*   prm = (int*)(ws + OFF_PERM);
  int*   cnk = (int*)(ws + OFF_CNKT);

  k_prep<<<dim3(257), dim3(256), 0, stream>>>(Wqkv, wqT, Wproj, wpT,
                                              pmask, pme, prm, cnk);
  k_gemm0<<<dim3(768), dim3(512), 0, stream>>>(x, wqT, bqkv, qb, kb, vtb);
  k_attn<<<dim3(512), dim3(512), 0, stream>>>(qb, kb, vtb, pme, prm, cnk, yb);
  k_gemm1<<<dim3(256), dim3(512), 0, stream>>>(yb, wpT, bproj, out);
}

// Round 22
// 79.172 us; speedup vs baseline: 1.0410x; 1.0410x over previous
//
#include <hip/hip_runtime.h>
#include <hip/hip_bf16.h>

// Problem constants
#define BB 8
#define TT_ 4
#define TSEQ 1024
#define CEMB 512
#define NH 8
#define HD 64

typedef __attribute__((ext_vector_type(8))) short bf16x8;
typedef __attribute__((ext_vector_type(4))) float f32x4;
typedef __attribute__((ext_vector_type(16))) float f32x16;

#define AS1 __attribute__((address_space(1)))
#define AS3 __attribute__((address_space(3)))

__device__ __forceinline__ void gload_lds16(const void* g, void* l) {
  __builtin_amdgcn_global_load_lds((const AS1 unsigned int*)g, (AS3 unsigned int*)l, 16, 0, 0);
}

__device__ __forceinline__ short f2b(float f) {
  union { float f; unsigned u; } v; v.f = f;
  unsigned r = v.u + 0x7FFFu + ((v.u >> 16) & 1u);
  return (short)(r >> 16);
}

// T12: hardware packed f32->bf16 convert (no builtin on gfx950; inline asm)
__device__ __forceinline__ unsigned pack2(float a, float b) {
  unsigned r;
  asm("v_cvt_pk_bf16_f32 %0, %1, %2" : "=v"(r) : "v"(a), "v"(b));
  return r;
}

// ---------------------------------------------------------------------------
// Prep kernel: W transposes (0-255) + mask/perm (block 256).
// ---------------------------------------------------------------------------
__global__ __launch_bounds__(256) void k_prep(
    const float* __restrict__ w0, short* __restrict__ t0,
    const float* __restrict__ w1, short* __restrict__ t1,
    const void* __restrict__ pin, int* __restrict__ pme,
    int* __restrict__ perm, int* __restrict__ chunk_nkt)
{
  __shared__ float tsh[64][65];
  const int bid = blockIdx.x;

  if (bid < 256) {
    const int z = (bid >= 192);
    const int tile = z ? (bid - 192) : bid;
    const int ntx = z ? 8 : 24;
    const float* w = z ? w1 : w0;
    short* wt = z ? t1 : t0;
    const int N = z ? 512 : 1536, K = 512;
    const int tx = threadIdx.x & 15, ty = threadIdx.x >> 4;
    const int n0 = (tile % ntx) * 64, k0 = (tile / ntx) * 64;
#pragma unroll
    for (int i = 0; i < 4; ++i) {
      int kr = i * 16 + ty;
      float4 v = *(const float4*)&w[(size_t)(k0 + kr) * N + n0 + tx * 4];
      tsh[tx * 4 + 0][kr] = v.x; tsh[tx * 4 + 1][kr] = v.y;
      tsh[tx * 4 + 2][kr] = v.z; tsh[tx * 4 + 3][kr] = v.w;
    }
    __syncthreads();
#pragma unroll
    for (int i = 0; i < 4; ++i) {
      int nr = i * 16 + ty;
      short4 o;
      o.x = f2b(tsh[nr][tx * 4 + 0]); o.y = f2b(tsh[nr][tx * 4 + 1]);
      o.z = f2b(tsh[nr][tx * 4 + 2]); o.w = f2b(tsh[nr][tx * 4 + 3]);
      *(short4*)&wt[(size_t)(n0 + nr) * K + k0 + tx * 4] = o;
    }
    return;
  }

  // ---- mask detect + expand + permutation (single block) ----
  __shared__ int bad_f32, any_f32, bad_i32, any_i32, bad_u16, any_u16;
  if (threadIdx.x == 0) { bad_f32 = any_f32 = bad_i32 = any_i32 = bad_u16 = any_u16 = 0; }
  __syncthreads();
  const unsigned char* pb = (const unsigned char*)pin;
  const float* pf = (const float*)pin;
  const int* pi = (const int*)pin;
  const unsigned short* ph = (const unsigned short*)pin;
  for (int i = threadIdx.x; i < 1024; i += 256) {
    float fv = pf[i];
    if (fv != 0.0f && fv != 1.0f) bad_f32 = 1;
    if (fv == 1.0f) any_f32 = 1;
    int iv = pi[i];
    if (iv != 0 && iv != 1) bad_i32 = 1;
    if (iv == 1) any_i32 = 1;
  }
  for (int i = threadIdx.x; i < 2048; i += 256) {
    unsigned short hv = ph[i];
    if (hv != 0 && hv != 0x3F80u && hv != 0x3C00u) bad_u16 = 1;
    if (hv == 0x3F80u || hv == 0x3C00u) any_u16 = 1;
  }
  __syncthreads();
  int mode = 3;
  if (!bad_f32 && any_f32) mode = 0;
  else if (!bad_i32 && any_i32) mode = 1;
  else if (!bad_u16 && any_u16) mode = 2;
  for (int i = threadIdx.x; i < TT_ * TSEQ; i += 256) {
    int v;
    if (mode == 0)      v = (pf[i] != 0.0f);
    else if (mode == 1) v = (pi[i] != 0);
    else if (mode == 2) v = (ph[i] != 0);
    else                v = (pb[i] != 0);
    pme[i] = v;
  }
  __syncthreads();

  const int w = threadIdx.x >> 6, lane = threadIdx.x & 63;
  {
    const int* rowp = pme + w * 1024;
    unsigned long long bal[16];
    int npm = 0;
#pragma unroll
    for (int g = 0; g < 16; ++g) {
      bal[g] = __ballot(rowp[g * 64 + lane] != 0);
      npm += __popcll(bal[g]);
    }
    int off_non = 0, off_pm = 1024 - npm;
#pragma unroll
    for (int g = 0; g < 16; ++g) {
      unsigned long long m = bal[g];
      int below = __popcll(m & ((1ull << lane) - 1ull));
      int ispm = (int)((m >> lane) & 1ull);
      int pos = ispm ? (off_pm + below) : (off_non + lane - below);
      perm[w * 1024 + pos] = g * 64 + lane;
      int c = __popcll(m);
      off_pm += c; off_non += 64 - c;
    }
  }
  __syncthreads();
  {
    const int tt = w, c = (lane >> 3) & 7, seg = lane & 7;
    int mx = 0;
#pragma unroll
    for (int i = 0; i < 16; ++i) {
      int q = perm[tt * 1024 + c * 128 + seg * 16 + i];
      int need = pme[tt * 1024 + q] ? 16 : ((q >> 6) + 1);
      mx = mx > need ? mx : need;
    }
#pragma unroll
    for (int s = 1; s < 8; s <<= 1) {
      int o = __shfl_xor(mx, s, 64);
      mx = mx > o ? mx : o;
    }
    if (seg == 0) chunk_nkt[tt * 8 + c] = mx;
  }
}

// ---------------------------------------------------------------------------
// GEMM0 (QKV): best-measured config — 128x128 tile, 8 waves (wave tile
// 32x64), BK=32, 3-buf depth-2 counted vmcnt. A direct from f32 x
// (reg-stage: 2 float4 -> cvt_pk -> 1 ds_write_b128/thread); B via 1
// gload_lds/thread. Q pre-scaled by 0.125*log2(e).
// ---------------------------------------------------------------------------
__global__ __launch_bounds__(512) void k_gemm0(
    const float* __restrict__ X, const short* __restrict__ Bt,
    const float* __restrict__ bias,
    short* __restrict__ qb, short* __restrict__ kb, short* __restrict__ vtb)
{
  __shared__ short As[3][128 * 32];
  __shared__ short Bs[3][128 * 32];
  const int tid = threadIdx.x, lane = tid & 63, w = tid >> 6;   // w: 0..7
  const int wm = w >> 1, wn = w & 1;        // wave tile 32x64
  const int idp = (blockIdx.x & 7) * 96 + (blockIdx.x >> 3);
  const int n0 = (idp % 12) * 128, m0 = (idp / 12) * 128;
  f32x4 acc[2][4] = {};
  const char* Xbase = (const char*)X + (size_t)m0 * 2048;   // f32 row = 2048B
  const char* Bbase = (const char*)Bt + (size_t)n0 * 1024;
  const int arow = tid >> 2;                 // 0..127
  const int asub = (tid & 3);                // 32B f32 sub-chunk

  float4 ar[2][2];                           // A reg double-buffer (static idx)

  auto aload = [&](int slot, int it) {       // 2x global_load_dwordx4 (vmcnt)
    const char* p = Xbase + (size_t)arow * 2048 + (size_t)it * 128 + asub * 32;
    ar[slot][0] = *(const float4*)p;
    ar[slot][1] = *(const float4*)(p + 16);
  };
  auto awrite = [&](int slot, int buf) {     // cvt + 1x ds_write_b128 (lgkm)
    union { unsigned u[4]; bf16x8 v; } o;
    float4 a = ar[slot][0], b2 = ar[slot][1];
    o.u[0] = pack2(a.x, a.y);  o.u[1] = pack2(a.z, a.w);
    o.u[2] = pack2(b2.x, b2.y); o.u[3] = pack2(b2.z, b2.w);
    *(bf16x8*)((char*)As[buf] + arow * 64 + asub * 16) = o.v;
  };
  auto stageB = [&](int buf, int it) {       // 1x gload_lds (vmcnt)
    gload_lds16(Bbase + (size_t)arow * 1024 + (size_t)it * 64 + asub * 16,
                (char*)Bs[buf] + w * 1024);
  };

  // prologue: queue after = [B0:1, A1:2, B1:1]; Abuf0 written.
  aload(0, 0);
  stageB(0, 0);
  aload(1, 1);
  asm volatile("s_waitcnt vmcnt(3)" ::: "memory");   // drain A(0)
  awrite(0, 0);
  stageB(1, 1);

#pragma unroll
  for (int it = 0; it < 16; ++it) {
    if (it < 15) asm volatile("s_waitcnt vmcnt(1)" ::: "memory");
    else         asm volatile("s_waitcnt vmcnt(0)" ::: "memory");
    if (it + 1 < 16) awrite((it + 1) & 1, (it + 1) % 3);
    if (it + 2 < 16) aload(it & 1, it + 2);          // slot (it+2)&1 == it&1
    asm volatile("s_waitcnt lgkmcnt(0)" ::: "memory");
    __builtin_amdgcn_s_barrier();
    if (it + 2 < 16) stageB((it + 2) % 3, it + 2);

    const short* Ab = As[it % 3];
    const short* Bb = Bs[it % 3];
    bf16x8 a[2], bfr[4];
#pragma unroll
    for (int mf = 0; mf < 2; ++mf)
      a[mf] = *(const bf16x8*)&Ab[(wm * 32 + mf * 16 + (lane & 15)) * 32 + (lane >> 4) * 8];
#pragma unroll
    for (int nf = 0; nf < 4; ++nf)
      bfr[nf] = *(const bf16x8*)&Bb[(wn * 64 + nf * 16 + (lane & 15)) * 32 + (lane >> 4) * 8];
#pragma unroll
    for (int mf = 0; mf < 2; ++mf)
#pragma unroll
      for (int nf = 0; nf < 4; ++nf)
        acc[mf][nf] = __builtin_amdgcn_mfma_f32_16x16x32_bf16(a[mf], bfr[nf], acc[mf][nf], 0, 0, 0);
  }

#pragma unroll
  for (int nf = 0; nf < 4; ++nf) {
    const int n_g = n0 + wn * 64 + nf * 16 + (lane & 15);
    const float bv = bias[n_g];
    const int which = n_g >> 9;
    const int c = n_g & 511;
    const int h = c >> 6, d = c & 63;
    const float qsc = (which == 0) ? 0.18033688011112043f : 1.0f;  // 0.125*log2(e)
#pragma unroll
    for (int mf = 0; mf < 2; ++mf) {
      const int mb = m0 + wm * 32 + mf * 16 + ((lane >> 4) << 2);
      const int b = mb >> 10, t0 = mb & 1023;
      const int b8h = b * NH + h;
      if (which == 2) {
        short4 pk;
        pk.x = f2b(acc[mf][nf][0] + bv);
        pk.y = f2b(acc[mf][nf][1] + bv);
        pk.z = f2b(acc[mf][nf][2] + bv);
        pk.w = f2b(acc[mf][nf][3] + bv);
        *(short4*)&vtb[((size_t)b8h * HD + d) * TSEQ + t0] = pk;
      } else {
        short* dst = (which == 0) ? qb : kb;
        size_t base = ((size_t)b8h * TSEQ + t0) * HD + d;
#pragma unroll
        for (int r = 0; r < 4; ++r)
          dst[base + (size_t)r * HD] = f2b((acc[mf][nf][r] + bv) * qsc);
      }
    }
  }
}

// ---------------------------------------------------------------------------
// GEMM1 (out-proj): 128x128 tile, 8 waves, 256 blocks, BK=32,
// 3-buf depth-2 counted vmcnt (2 loads/thread/stage -> steady vmcnt(2)).
// ---------------------------------------------------------------------------
__global__ __launch_bounds__(512) void k_gemm1(
    const short* __restrict__ A, const short* __restrict__ Bt,
    const float* __restrict__ bias, float* __restrict__ fout)
{
  __shared__ short As[3][128 * 32];
  __shared__ short Bs[3][128 * 32];
  const int tid = threadIdx.x, lane = tid & 63, w = tid >> 6;
  const int wm = w >> 1, wn = w & 1;
  const int idp = (blockIdx.x & 7) * 32 + (blockIdx.x >> 3);
  const int n0 = (idp % 4) * 128, m0 = (idp / 4) * 128;
  f32x4 acc[2][4] = {};
  const char* Abase = (const char*)A + (size_t)m0 * 1024;
  const char* Bbase = (const char*)Bt + (size_t)n0 * 1024;
  const int arow = tid >> 2, asub = tid & 3;

  auto stage = [&](int buf, int it) {        // 2 loads/thread
    gload_lds16(Abase + (size_t)arow * 1024 + (size_t)it * 64 + asub * 16,
                (char*)As[buf] + w * 1024);
    gload_lds16(Bbase + (size_t)arow * 1024 + (size_t)it * 64 + asub * 16,
                (char*)Bs[buf] + w * 1024);
  };

  stage(0, 0);
  stage(1, 1);
#pragma unroll
  for (int it = 0; it < 16; ++it) {
    if (it < 15) asm volatile("s_waitcnt vmcnt(2)\n\ts_barrier" ::: "memory");
    else         asm volatile("s_waitcnt vmcnt(0)\n\ts_barrier" ::: "memory");
    if (it + 2 < 16) stage((it + 2) % 3, it + 2);
    const short* Ab = As[it % 3];
    const short* Bb = Bs[it % 3];
    bf16x8 a[2], bfr[4];
#pragma unroll
    for (int mf = 0; mf < 2; ++mf)
      a[mf] = *(const bf16x8*)&Ab[(wm * 32 + mf * 16 + (lane & 15)) * 32 + (lane >> 4) * 8];
#pragma unroll
    for (int nf = 0; nf < 4; ++nf)
      bfr[nf] = *(const bf16x8*)&Bb[(wn * 64 + nf * 16 + (lane & 15)) * 32 + (lane >> 4) * 8];
#pragma unroll
    for (int mf = 0; mf < 2; ++mf)
#pragma unroll
      for (int nf = 0; nf < 4; ++nf)
        acc[mf][nf] = __builtin_amdgcn_mfma_f32_16x16x32_bf16(a[mf], bfr[nf], acc[mf][nf], 0, 0, 0);
  }

#pragma unroll
  for (int nf = 0; nf < 4; ++nf) {
    const int n_g = n0 + wn * 64 + nf * 16 + (lane & 15);
    const float bv = bias[n_g];
#pragma unroll
    for (int mf = 0; mf < 2; ++mf) {
      const int mb = m0 + wm * 32 + mf * 16 + ((lane >> 4) << 2);
#pragma unroll
      for (int r = 0; r < 4; ++r)
        fout[(size_t)(mb + r) * 512 + n_g] = acc[mf][nf][r] + bv;
    }
  }
}

// ---------------------------------------------------------------------------
// Flash attention — split-K within block, LDS-staged K/V, tree reductions,
// defer-max, heavy-first chunks, y via LDS coalesce.
// ---------------------------------------------------------------------------
__device__ __forceinline__ void pv_step(
    f32x16 p, int sub, int hi, int lq, const char* Vsb, f32x16& o0, f32x16& o1)
{
  unsigned P2[8];
#pragma unroll
  for (int i = 0; i < 8; ++i) P2[i] = pack2(p[2 * i], p[2 * i + 1]);
  unsigned e0 = __shfl_xor(hi ? P2[0] : P2[2], 32, 64);
  unsigned e1 = __shfl_xor(hi ? P2[1] : P2[3], 32, 64);
  unsigned e2 = __shfl_xor(hi ? P2[4] : P2[6], 32, 64);
  unsigned e3 = __shfl_xor(hi ? P2[5] : P2[7], 32, 64);
  union { unsigned u[4]; bf16x8 v; } f0, f1;
  f0.u[0] = hi ? e0 : P2[0]; f0.u[1] = hi ? e1 : P2[1];
  f0.u[2] = hi ? P2[2] : e0; f0.u[3] = hi ? P2[3] : e1;
  f1.u[0] = hi ? e2 : P2[4]; f1.u[1] = hi ? e3 : P2[5];
  f1.u[2] = hi ? P2[6] : e2; f1.u[3] = hi ? P2[7] : e3;
  __builtin_amdgcn_s_setprio(1);
#pragma unroll
  for (int dt = 0; dt < 2; ++dt) {
    int row = dt * 32 + lq;
    bf16x8 v0 = *(const bf16x8*)(Vsb + row * 128 + ((4 * sub + hi) ^ (row & 7)) * 16);
    bf16x8 v1 = *(const bf16x8*)(Vsb + row * 128 + ((4 * sub + 2 + hi) ^ (row & 7)) * 16);
    f32x16& o = dt ? o1 : o0;
    o = __builtin_amdgcn_mfma_f32_32x32x16_bf16(v0, f0.v, o, 0, 0, 0);
    o = __builtin_amdgcn_mfma_f32_32x32x16_bf16(v1, f1.v, o, 0, 0, 0);
  }
  __builtin_amdgcn_s_setprio(0);
}

__global__ __launch_bounds__(512) void k_attn(
    const short* __restrict__ qg, const short* __restrict__ kg,
    const short* __restrict__ vtg, const int* __restrict__ pme,
    const int* __restrict__ perm, const int* __restrict__ chunk_nkt,
    short* __restrict__ yb)
{
  __shared__ char smem[65536];
  const int tid = threadIdx.x, lane = tid & 63, w = tid >> 6;   // w: 0..7
  const int g = w >> 2;                         // KV-parity group
  const int hi = lane >> 5, lq = lane & 31;
  const int id = blockIdx.x;
  const int bh = id & 63, b = bh >> 3, h = bh & 7, tt = b & 3;
  const int chunk = 7 - (id >> 6);              // heavy chunks dispatched first
  const char* Qb = (const char*)(qg + (size_t)bh * TSEQ * HD);
  const char* Kb = (const char*)(kg + (size_t)bh * TSEQ * HD);
  const char* Vb = (const char*)(vtg + (size_t)bh * HD * TSEQ);

  const int stg_row = ((w & 3) << 3) + (lane >> 3);    // 0..31
  const int stg_cl = (lane & 7) ^ ((lane >> 3) & 7);   // pre-swizzled source chunk

  auto stage = [&](int buf, int kt) {                  // 4 loads/thread
#pragma unroll
    for (int is = 0; is < 2; ++is) {
      int row = is * 32 + stg_row;
      gload_lds16(Kb + (size_t)(kt * 64 + row) * 128 + stg_cl * 16,
                  smem + buf * 8192 + is * 4096 + (w & 3) * 1024);
      gload_lds16(Vb + (size_t)row * 2048 + kt * 128 + stg_cl * 16,
                  smem + 32768 + buf * 8192 + is * 4096 + (w & 3) * 1024);
    }
  };

  const int nkt = chunk_nkt[tt * 8 + chunk];
  const int q_g = perm[tt * 1024 + chunk * 128 + (w & 3) * 32 + lq];
  const int pmrow = pme[tt * TSEQ + q_g];

  if (g < nkt) stage(g * 2, g);   // prologue: A stages tile 0, B tile 1

  int wmq = q_g, wnq = q_g;
#pragma unroll
  for (int s = 1; s < 64; s <<= 1) {
    wmq = max(wmq, __shfl_xor(wmq, s, 64));
    wnq = min(wnq, __shfl_xor(wnq, s, 64));
  }
  const int whaspm = __any(pmrow != 0);

  bf16x8 qf[4];
#pragma unroll
  for (int dk = 0; dk < 4; ++dk)
    qf[dk] = *(const bf16x8*)(Qb + (size_t)q_g * 128 + dk * 32 + hi * 16);

  float mrun = -1e30f, lrun = 0.0f;
  f32x16 o0 = {}, o1 = {};

  const int niter = (nkt + 1) >> 1;
  for (int i = 0; i < niter; ++i) {
    asm volatile("s_waitcnt vmcnt(0)" ::: "memory");
    __builtin_amdgcn_s_barrier();
    const int kt = 2 * i + g;
    if (kt + 2 < nkt) stage(g * 2 + ((i + 1) & 1), kt + 2);

    const int kb_ = kt * 64;
    if (kt < nkt && (kb_ <= wmq || whaspm)) {
      const char* Ksb = smem + (g * 2 + (i & 1)) * 8192;
      const char* Vsb = smem + 32768 + (g * 2 + (i & 1)) * 8192;

      f32x16 s0 = {}, s1 = {};
      __builtin_amdgcn_s_setprio(1);
#pragma unroll
      for (int dk = 0; dk < 4; ++dk) {
        int row0 = lq, row1 = 32 + lq;
        bf16x8 kf0 = *(const bf16x8*)(Ksb + row0 * 128 + ((2 * dk + hi) ^ (row0 & 7)) * 16);
        bf16x8 kf1 = *(const bf16x8*)(Ksb + row1 * 128 + ((2 * dk + hi) ^ (row1 & 7)) * 16);
        s0 = __builtin_amdgcn_mfma_f32_32x32x16_bf16(kf0, qf[dk], s0, 0, 0, 0);
        s1 = __builtin_amdgcn_mfma_f32_32x32x16_bf16(kf1, qf[dk], s1, 0, 0, 0);
      }
      __builtin_amdgcn_s_setprio(0);

      if (kb_ + 63 <= wnq) {
        // fully attended
      } else if (kb_ > wmq) {
#pragma unroll
        for (int r = 0; r < 16; ++r) {
          s0[r] = pmrow ? s0[r] : -1e30f;
          s1[r] = pmrow ? s1[r] : -1e30f;
        }
      } else {
#pragma unroll
        for (int r = 0; r < 16; ++r) {
          int crow = (r & 3) + 8 * (r >> 2) + 4 * hi;
          s0[r] = ((kb_ + crow <= q_g) || pmrow) ? s0[r] : -1e30f;
          s1[r] = ((kb_ + 32 + crow <= q_g) || pmrow) ? s1[r] : -1e30f;
        }
      }

      float tm[16];
#pragma unroll
      for (int r = 0; r < 16; ++r) tm[r] = fmaxf(s0[r], s1[r]);
#pragma unroll
      for (int st = 8; st >= 1; st >>= 1)
#pragma unroll
        for (int r = 0; r < 8; ++r)
          if (r < st) tm[r] = fmaxf(tm[r], tm[r + st]);
      float mx = fmaxf(tm[0], __shfl_xor(tm[0], 32, 64));
      if (!__all(mx <= mrun + 8.0f)) {
        float nm = fmaxf(mrun, mx);
        float sc = __builtin_amdgcn_exp2f(mrun - nm);
        lrun *= sc;
#pragma unroll
        for (int r = 0; r < 16; ++r) { o0[r] *= sc; o1[r] *= sc; }
        mrun = nm;
      }
#pragma unroll
      for (int r = 0; r < 16; ++r) s0[r] = __builtin_amdgcn_exp2f(s0[r] - mrun);
#pragma unroll
      for (int r = 0; r < 16; ++r) s1[r] = __builtin_amdgcn_exp2f(s1[r] - mrun);
      float ts[16];
#pragma unroll
      for (int r = 0; r < 16; ++r) ts[r] = s0[r] + s1[r];
#pragma unroll
      for (int st = 8; st >= 1; st >>= 1)
#pragma unroll
        for (int r = 0; r < 8; ++r)
          if (r < st) ts[r] = ts[r] + ts[r + st];
      lrun += ts[0] + __shfl_xor(ts[0], 32, 64);

      pv_step(s0, 0, hi, lq, Vsb, o0, o1);
      pv_step(s1, 1, hi, lq, Vsb, o0, o1);
    }
  }

  // ---- merge groups A and B, stage y row-major in LDS, coalesced store ----
  __syncthreads();
  float* mg = (float*)smem;               // [256][34]: m, l, o[32]  (34816 B)
  short* ys = (short*)(smem + 36864);     // [128][72] bf16 rows     (18432 B)
  const int idx = (w & 3) * 64 + lane;
  if (g == 1) {
    mg[idx * 34 + 0] = mrun;
    mg[idx * 34 + 1] = lrun;
#pragma unroll
    for (int j = 0; j < 16; ++j) mg[idx * 34 + 2 + j] = o0[j];
#pragma unroll
    for (int j = 0; j < 16; ++j) mg[idx * 34 + 18 + j] = o1[j];
  }
  __syncthreads();
  if (g == 0) {
    const float mB = mg[idx * 34 + 0], lB = mg[idx * 34 + 1];
    const float m = fmaxf(mrun, mB);
    const float wa = __builtin_amdgcn_exp2f(mrun - m);
    const float wb = __builtin_amdgcn_exp2f(mB - m);
    const float linv = 1.0f / (lrun * wa + lB * wb);
    const float fa = wa * linv, fb = wb * linv;
    short* yl = ys + ((w & 3) * 32 + lq) * 72;
#pragma unroll
    for (int dt = 0; dt < 2; ++dt) {
      const f32x16& o = dt ? o1 : o0;
      const int ob = dt ? 18 : 2;
#pragma unroll
      for (int gg = 0; gg < 4; ++gg) {
        short4 pk;
        pk.x = f2b(o[4 * gg + 0] * fa + mg[idx * 34 + ob + 4 * gg + 0] * fb);
        pk.y = f2b(o[4 * gg + 1] * fa + mg[idx * 34 + ob + 4 * gg + 1] * fb);
        pk.z = f2b(o[4 * gg + 2] * fa + mg[idx * 34 + ob + 4 * gg + 2] * fb);
        pk.w = f2b(o[4 * gg + 3] * fa + mg[idx * 34 + ob + 4 * gg + 3] * fb);
        *(short4*)(yl + dt * 32 + 8 * gg + 4 * hi) = pk;
      }
    }
  }
  __syncthreads();
  {
    const int row = tid >> 2, seg = tid & 3;      // 4 threads/row x 32B
    const int q_row = perm[tt * 1024 + chunk * 128 + row];
    short* dst = yb + ((size_t)b * TSEQ + q_row) * CEMB + h * HD + seg * 16;
    *(bf16x8*)dst = *(const bf16x8*)&ys[row * 72 + seg * 16];
    *(bf16x8*)(dst + 8) = *(const bf16x8*)&ys[row * 72 + seg * 16 + 8];
  }
}

// ---------------------------------------------------------------------------
extern "C" void kernel_launch(void* const* d_in, const int* in_sizes, int n_in,
                              void* d_out, int out_size, void* d_ws, size_t ws_size,
                              hipStream_t stream) {
  const float* x     = (const float*)d_in[0];
  const void*  pmask = d_in[1];
  const float* Wqkv  = (const float*)d_in[2];
  const float* bqkv  = (const float*)d_in[3];
  const float* Wproj = (const float*)d_in[4];
  const float* bproj = (const float*)d_in[5];
  float* out = (float*)d_out;
  char* ws = (char*)d_ws;

  const size_t OFF_WQT  = 8388608;    // 1.5 MiB
  const size_t OFF_WPT  = 9961472;    // 0.5 MiB
  const size_t OFF_Q    = 10485760;   // 8 MiB
  const size_t OFF_K    = 18874368;   // 8 MiB
  const size_t OFF_VT   = 27262976;   // 8 MiB
  const size_t OFF_Y    = 35651584;   // 8 MiB
  const size_t OFF_PM   = 44040192;   // 16 KiB
  const size_t OFF_PERM = 44056576;   // 16 KiB
  const size_t OFF_CNKT = 44072960;   // 128 B
  const size_t NEED     = 44073984;
  if (ws_size < NEED) return;

  short* wqT = (short*)(ws + OFF_WQT);
  short* wpT = (short*)(ws + OFF_WPT);
  short* qb  = (short*)(ws + OFF_Q);
  short* kb  = (short*)(ws + OFF_K);
  short* vtb = (short*)(ws + OFF_VT);
  short* yb  = (short*)(ws + OFF_Y);
  int*   pme = (int*)(ws + OFF_PM);
  int*   prm = (int*)(ws + OFF_PERM);
  int*   cnk = (int*)(ws + OFF_CNKT);

  k_prep<<<dim3(257), dim3(256), 0, stream>>>(Wqkv, wqT, Wproj, wpT,
                                              pmask, pme, prm, cnk);
  k_gemm0<<<dim3(768), dim3(512), 0, stream>>>(x, wqT, bqkv, qb, kb, vtb);
  k_attn<<<dim3(512), dim3(512), 0, stream>>>(qb, kb, vtb, pme, prm, cnk, yb);
  k_gemm1<<<dim3(256), dim3(512), 0, stream>>>(yb, wpT, bproj, out);
}